// Round 8
// baseline (805.637 us; speedup 1.0000x reference)
//
#include <hip/hip_runtime.h>

// GraphConv: out[t] += input[s] * (esgn*enorm), 3.2M edges, 100K nodes, D=32 fp32.
// Round 19: R18's deterministic partition landed (289->201us, partition family
// gone from top-5; bucket_accum 58us now dominates). bucket_accum was reading
// recs TWICE (hist + sort-scatter) plus an 8-round scan, all to enable sorted
// register accumulation -- but the SPAN=128 output tile is only 128x32 f32
// ~= 16KB. New bucket_accum: edge-parallel direct accumulate into a padded
// (stride 33 -> ~2-way banks) LDS f32 tile via fire-and-forget ds_add_f32,
// 8 lanes/edge, 4-deep unroll. Deletes hist pass, scan, sort, CAP overflow
// path. Parallelism: 782 blocks x 128 groups = 100K chains of ~32 edges
// (seg_accum-like; NOT R12's 6K chains). Everything else frozen (verified).
// Pipeline: hist -> scan1 -> bscan -> scatter -> bucket_accum.

#define G    256          // edge chunks / scatter blocks
#define KMAX 1024         // max buckets (span 128 -> n_nodes <= 131072)
#define SPAN_SHIFT 7
#define SPAN 128
#define TSTRIDE 33        // LDS tile row stride (odd -> banks spread)
#define NB   256

// Per-chunk histogram: cnt[g*KMAX + b]. Coalesced matrix write, no atomics
// beyond LDS.
__global__ __launch_bounds__(1024) void hist_kernel(
    const int* __restrict__ tidx, int* __restrict__ cnt,
    int n_edges, int epb, int vec)
{
    __shared__ int lh[KMAX];
    int g = blockIdx.x, t = threadIdx.x;
    lh[t] = 0;
    __syncthreads();
    int beg = g * epb;
    int lim = beg + epb; if (lim > n_edges) lim = n_edges;
    if (vec) {
        int nq = (lim > beg) ? ((lim - beg) >> 2) : 0;
        for (int q = t; q < nq; q += 1024) {
            int4 tn = *(const int4*)(tidx + beg + q * 4);
            atomicAdd(&lh[tn.x >> SPAN_SHIFT], 1);
            atomicAdd(&lh[tn.y >> SPAN_SHIFT], 1);
            atomicAdd(&lh[tn.z >> SPAN_SHIFT], 1);
            atomicAdd(&lh[tn.w >> SPAN_SHIFT], 1);
        }
        for (int e = beg + (nq << 2) + t; e < lim; e += 1024)
            atomicAdd(&lh[tidx[e] >> SPAN_SHIFT], 1);
    } else {
        for (int e = beg + t; e < lim; e += 1024)
            atomicAdd(&lh[tidx[e] >> SPAN_SHIFT], 1);
    }
    __syncthreads();
    cnt[g * KMAX + t] = lh[t];
}

// Per-bucket exclusive scan over the G chunk counts -> pref[g][b], tot[b].
__global__ __launch_bounds__(G) void scan1_kernel(
    const int* __restrict__ cnt, int* __restrict__ pref, int* __restrict__ tot)
{
    __shared__ int part[G];
    int b = blockIdx.x, t = threadIdx.x;
    int c = cnt[t * KMAX + b];
    part[t] = c;
    __syncthreads();
    for (int off = 1; off < G; off <<= 1) {
        int v = (t >= off) ? part[t - off] : 0;
        __syncthreads();
        part[t] += v;
        __syncthreads();
    }
    pref[t * KMAX + b] = part[t] - c;
    if (t == G - 1) tot[b] = part[t];
}

// Exclusive scan over KMAX bucket totals -> bbase[0..KMAX] (all entries
// written; entries >= K act as end sentinels since tot[b>=K] == 0).
__global__ __launch_bounds__(KMAX) void bscan_kernel(
    const int* __restrict__ tot, int* __restrict__ bbase)
{
    __shared__ int part[KMAX];
    int t = threadIdx.x;
    int c = tot[t];
    part[t] = c;
    __syncthreads();
    for (int off = 1; off < KMAX; off <<= 1) {
        int v = (t >= off) ? part[t - off] : 0;
        __syncthreads();
        part[t] += v;
        __syncthreads();
    }
    bbase[t] = part[t] - c;
    if (t == KMAX - 1) bbase[KMAX] = part[t];
}

// Deterministic scatter: block g owns chunk g; position = gbase[b] + LDS rank.
// No global atomics; one pass.
__global__ __launch_bounds__(1024) void scatter_kernel(
    const int* __restrict__ sidx, const int* __restrict__ tidx,
    const float* __restrict__ enorm, const float* __restrict__ esgn,
    const int* __restrict__ bbase, const int* __restrict__ pref,
    int2* __restrict__ recs, int n_edges, int epb, int vec)
{
    __shared__ int gbase[KMAX];
    __shared__ int lh[KMAX];
    int g = blockIdx.x, t = threadIdx.x;
    gbase[t] = bbase[t] + pref[g * KMAX + t];
    lh[t] = 0;
    __syncthreads();
    int beg = g * epb;
    int lim = beg + epb; if (lim > n_edges) lim = n_edges;

    #define SCAT_EDGE(tn_, sn_, w_) {                                        \
        int b_ = (tn_) >> SPAN_SHIFT;                                        \
        int rank_ = atomicAdd(&lh[b_], 1);                                   \
        unsigned rec_ = ((unsigned)(sn_) << SPAN_SHIFT) |                    \
                        (unsigned)((tn_) & (SPAN - 1));                      \
        recs[gbase[b_] + rank_] = make_int2((int)rec_, __float_as_int(w_)); }

    if (vec) {
        int nq = (lim > beg) ? ((lim - beg) >> 2) : 0;
        for (int q = t; q < nq; q += 1024) {
            int e = beg + q * 4;
            int4   tn = *(const int4*)(tidx + e);
            int4   sn = *(const int4*)(sidx + e);
            float4 nw = *(const float4*)(enorm + e);
            float4 sw = *(const float4*)(esgn + e);
            SCAT_EDGE(tn.x, sn.x, nw.x * sw.x);
            SCAT_EDGE(tn.y, sn.y, nw.y * sw.y);
            SCAT_EDGE(tn.z, sn.z, nw.z * sw.z);
            SCAT_EDGE(tn.w, sn.w, nw.w * sw.w);
        }
        for (int e = beg + (nq << 2) + t; e < lim; e += 1024) {
            int tn = tidx[e]; int sn = sidx[e];
            float w = enorm[e] * esgn[e];
            SCAT_EDGE(tn, sn, w);
        }
    } else {
        for (int e = beg + t; e < lim; e += 1024) {
            int tn = tidx[e]; int sn = sidx[e];
            float w = enorm[e] * esgn[e];
            SCAT_EDGE(tn, sn, w);
        }
    }
    #undef SCAT_EDGE
}

// R19 direct accumulate: one block per bucket (128 nodes). Padded LDS f32
// tile (128 x 33, stride 33 -> node term spreads banks); edge-parallel,
// 8 lanes/edge, fire-and-forget LDS float atomics, 4-deep unroll. Handles
// any bucket size (no CAP, no overflow path).
__global__ __launch_bounds__(1024) void bucket_accum(
    const float* __restrict__ input, const int2* __restrict__ recs,
    const int* __restrict__ bbase, float* __restrict__ out, int n_nodes)
{
    __shared__ float tile[SPAN * TSTRIDE];     // 16.5 KB
    int b = blockIdx.x;
    int t = threadIdx.x;
    int bstart = bbase[b], bend = bbase[b + 1];
    int base_node = b << SPAN_SHIFT;

    for (int i = t; i < SPAN * TSTRIDE; i += 1024) tile[i] = 0.f;
    __syncthreads();

    int grp  = t >> 3;                 // 128 edge-groups per block
    int lane = t & 7;                  // feature quad index
    int slot = lane << 2;              // feature offset 0,4,...,28

    #define ACC_EDGE(r_) {                                                   \
        float w_ = __int_as_float((r_).y);                                   \
        int s_ = (int)(((unsigned)(r_).x) >> SPAN_SHIFT);                    \
        int ln_ = (r_).x & (SPAN - 1);                                       \
        float4 v_ = ((const float4*)(input + (size_t)s_ * 32))[lane];        \
        float* tp_ = &tile[ln_ * TSTRIDE + slot];                            \
        atomicAdd(tp_ + 0, w_ * v_.x);                                       \
        atomicAdd(tp_ + 1, w_ * v_.y);                                       \
        atomicAdd(tp_ + 2, w_ * v_.z);                                       \
        atomicAdd(tp_ + 3, w_ * v_.w); }

    int i = bstart + grp;
    for (; i + 384 < bend; i += 512) {
        int2 r0 = recs[i];
        int2 r1 = recs[i + 128];
        int2 r2 = recs[i + 256];
        int2 r3 = recs[i + 384];
        ACC_EDGE(r0);
        ACC_EDGE(r1);
        ACC_EDGE(r2);
        ACC_EDGE(r3);
    }
    for (; i < bend; i += 128) {
        int2 r = recs[i];
        ACC_EDGE(r);
    }
    #undef ACC_EDGE
    __syncthreads();

    // Coalesced write-out: out linear = base_node*32 + j; LDS banks spread
    // by the +node term of stride 33.
    for (int j = t; j < SPAN * 32; j += 1024) {
        int node = j >> 5;
        int gn = base_node + node;
        if (gn < n_nodes)
            out[(size_t)base_node * 32 + j] = tile[node * TSTRIDE + (j & 31)];
    }
}

// Last-resort fallback (R3): direct atomic scatter.
__global__ __launch_bounds__(NB) void graphconv_scatter(
    const float* __restrict__ input, const int* __restrict__ sidx,
    const int* __restrict__ tidx, const float* __restrict__ enorm,
    const float* __restrict__ esgn, float* __restrict__ out, int n_edges)
{
    int t = blockIdx.x * NB + threadIdx.x;
    int e = t >> 3;
    int sub = t & 7;
    if (e >= n_edges) return;
    int s = sidx[e];
    int d = tidx[e];
    float w = enorm[e] * esgn[e];
    const float4* src = (const float4*)(input + (size_t)s * 32);
    float4 v = src[sub];
    float* op = out + (size_t)d * 32 + sub * 4;
    atomicAdd(op + 0, v.x * w);
    atomicAdd(op + 1, v.y * w);
    atomicAdd(op + 2, v.z * w);
    atomicAdd(op + 3, v.w * w);
}

extern "C" void kernel_launch(void* const* d_in, const int* in_sizes, int n_in,
                              void* d_out, int out_size, void* d_ws, size_t ws_size,
                              hipStream_t stream) {
    const float* input = (const float*)d_in[0];
    const int*   eidx  = (const int*)d_in[1];   // int64 in reference -> int32 here
    const float* enorm = (const float*)d_in[2];
    const float* esgn  = (const float*)d_in[3];
    float*       out   = (float*)d_out;

    int n_edges = in_sizes[1] / 2;             // eidx is (2, n_edges)
    int n_nodes = in_sizes[0] / 32;            // input is (n_nodes, 32)
    const int* sidx = eidx;
    const int* tidx = eidx + n_edges;

    int K = (n_nodes + SPAN - 1) >> SPAN_SHIFT;   // 782 for 100K nodes

    // Workspace: recs[E int2] | cnt[G*KMAX] | pref[G*KMAX] | tot[KMAX] | bbase[KMAX+1]
    size_t need = (size_t)n_edges * 8 +
                  ((size_t)2 * G * KMAX + 2 * KMAX + 1) * 4;

    if (ws_size >= need && K <= KMAX) {
        int2* recs  = (int2*)d_ws;
        int*  cnt   = (int*)(recs + n_edges);
        int*  pref  = cnt + (size_t)G * KMAX;
        int*  tot   = pref + (size_t)G * KMAX;
        int*  bbase = tot + KMAX;

        // chunk size: multiple of 4 so vector loads stay 16B-aligned
        int epb = ((n_edges + G - 1) / G + 3) & ~3;
        int vec = ((n_edges & 3) == 0 &&
                   (((uintptr_t)tidx | (uintptr_t)sidx |
                     (uintptr_t)enorm | (uintptr_t)esgn) & 15) == 0) ? 1 : 0;

        hist_kernel   <<<G,    1024, 0, stream>>>(tidx, cnt, n_edges, epb, vec);
        scan1_kernel  <<<KMAX, G,    0, stream>>>(cnt, pref, tot);
        bscan_kernel  <<<1,    KMAX, 0, stream>>>(tot, bbase);
        scatter_kernel<<<G,    1024, 0, stream>>>(sidx, tidx, enorm, esgn,
                                                  bbase, pref, recs,
                                                  n_edges, epb, vec);
        bucket_accum  <<<K,    1024, 0, stream>>>(input, recs, bbase,
                                                  out, n_nodes);
    } else {
        hipMemsetAsync(d_out, 0, (size_t)out_size * sizeof(float), stream);
        size_t threads_total = (size_t)n_edges * 8;
        int grid = (int)((threads_total + NB - 1) / NB);
        graphconv_scatter<<<grid, NB, 0, stream>>>(input, sidx, tidx, enorm, esgn,
                                                   out, n_edges);
    }
}

// Round 10
// 220.726 us; speedup vs baseline: 3.6499x; 3.6499x over previous
//
#include <hip/hip_runtime.h>

// GraphConv: out[t] += input[s] * (esgn*enorm), 3.2M edges, 100K nodes, D=32 fp32.
// Round 21 == Round 20 resubmitted (R9 bench was GPUAcquisitionTimeout infra
// failure; kernel never ran). R19 proved LDS float atomicAdd is a serialized
// RMW path on this toolchain (673us, VALU 1.2%, HBM 3.3%, 0 bank conflicts --
// identical dead signature to R12's 691us despite 16x more chains). This is
// R18's verified sort-then-register-accumulate bucket_accum with two deltas:
//   (a) single global read of recs: stage <=6 records/thread in statically-
//       indexed registers (rule-20 safe), hist+scatter from regs. -25.6MB HBM.
//   (b) scan1+bscan merged into one 1-block scanAB kernel (pref/bbase layouts
//       unchanged): 5 -> 4 launches.
// Pipeline: hist -> scanAB -> scatter -> bucket_accum.

#define G    256          // edge chunks / scatter blocks
#define KMAX 1024         // max buckets (span 128 -> n_nodes <= 131072)
#define SPAN_SHIFT 7
#define SPAN 128
#define CAP  6144         // bucket_accum LDS record capacity (48KB)
#define NB   256

// Per-chunk histogram: cnt[g*KMAX + b]. Coalesced matrix write, no atomics
// beyond LDS.
__global__ __launch_bounds__(1024) void hist_kernel(
    const int* __restrict__ tidx, int* __restrict__ cnt,
    int n_edges, int epb, int vec)
{
    __shared__ int lh[KMAX];
    int g = blockIdx.x, t = threadIdx.x;
    lh[t] = 0;
    __syncthreads();
    int beg = g * epb;
    int lim = beg + epb; if (lim > n_edges) lim = n_edges;
    if (vec) {
        int nq = (lim > beg) ? ((lim - beg) >> 2) : 0;
        for (int q = t; q < nq; q += 1024) {
            int4 tn = *(const int4*)(tidx + beg + q * 4);
            atomicAdd(&lh[tn.x >> SPAN_SHIFT], 1);
            atomicAdd(&lh[tn.y >> SPAN_SHIFT], 1);
            atomicAdd(&lh[tn.z >> SPAN_SHIFT], 1);
            atomicAdd(&lh[tn.w >> SPAN_SHIFT], 1);
        }
        for (int e = beg + (nq << 2) + t; e < lim; e += 1024)
            atomicAdd(&lh[tidx[e] >> SPAN_SHIFT], 1);
    } else {
        for (int e = beg + t; e < lim; e += 1024)
            atomicAdd(&lh[tidx[e] >> SPAN_SHIFT], 1);
    }
    __syncthreads();
    cnt[g * KMAX + t] = lh[t];
}

// R20: fused column-scan + bucket-base scan, single block.
// Thread t owns bucket t: running sum over g (coalesced per-g rows) writes
// pref[g][t]; then 1024-wide LDS scan of totals -> bbase[0..KMAX].
__global__ __launch_bounds__(KMAX) void scanAB_kernel(
    const int* __restrict__ cnt, int* __restrict__ pref, int* __restrict__ bbase)
{
    __shared__ int part[KMAX];
    int t = threadIdx.x;
    int run = 0;
    #pragma unroll 4
    for (int g = 0; g < G; ++g) {
        int c = cnt[g * KMAX + t];
        pref[g * KMAX + t] = run;
        run += c;
    }
    part[t] = run;
    __syncthreads();
    for (int off = 1; off < KMAX; off <<= 1) {
        int v = (t >= off) ? part[t - off] : 0;
        __syncthreads();
        part[t] += v;
        __syncthreads();
    }
    bbase[t] = part[t] - run;
    if (t == KMAX - 1) bbase[KMAX] = part[t];
}

// Deterministic scatter: block g owns chunk g; position = gbase[b] + LDS rank.
// No global atomics; one pass. (Verified R18.)
__global__ __launch_bounds__(1024) void scatter_kernel(
    const int* __restrict__ sidx, const int* __restrict__ tidx,
    const float* __restrict__ enorm, const float* __restrict__ esgn,
    const int* __restrict__ bbase, const int* __restrict__ pref,
    int2* __restrict__ recs, int n_edges, int epb, int vec)
{
    __shared__ int gbase[KMAX];
    __shared__ int lh[KMAX];
    int g = blockIdx.x, t = threadIdx.x;
    gbase[t] = bbase[t] + pref[g * KMAX + t];
    lh[t] = 0;
    __syncthreads();
    int beg = g * epb;
    int lim = beg + epb; if (lim > n_edges) lim = n_edges;

    #define SCAT_EDGE(tn_, sn_, w_) {                                        \
        int b_ = (tn_) >> SPAN_SHIFT;                                        \
        int rank_ = atomicAdd(&lh[b_], 1);                                   \
        unsigned rec_ = ((unsigned)(sn_) << SPAN_SHIFT) |                    \
                        (unsigned)((tn_) & (SPAN - 1));                      \
        recs[gbase[b_] + rank_] = make_int2((int)rec_, __float_as_int(w_)); }

    if (vec) {
        int nq = (lim > beg) ? ((lim - beg) >> 2) : 0;
        for (int q = t; q < nq; q += 1024) {
            int e = beg + q * 4;
            int4   tn = *(const int4*)(tidx + e);
            int4   sn = *(const int4*)(sidx + e);
            float4 nw = *(const float4*)(enorm + e);
            float4 sw = *(const float4*)(esgn + e);
            SCAT_EDGE(tn.x, sn.x, nw.x * sw.x);
            SCAT_EDGE(tn.y, sn.y, nw.y * sw.y);
            SCAT_EDGE(tn.z, sn.z, nw.z * sw.z);
            SCAT_EDGE(tn.w, sn.w, nw.w * sw.w);
        }
        for (int e = beg + (nq << 2) + t; e < lim; e += 1024) {
            int tn = tidx[e]; int sn = sidx[e];
            float w = enorm[e] * esgn[e];
            SCAT_EDGE(tn, sn, w);
        }
    } else {
        for (int e = beg + t; e < lim; e += 1024) {
            int tn = tidx[e]; int sn = sidx[e];
            float w = enorm[e] * esgn[e];
            SCAT_EDGE(tn, sn, w);
        }
    }
    #undef SCAT_EDGE
}

// Fused node-sort + accumulate, one block per bucket (128 nodes).
// R20: records staged ONCE from global into 6 statically-indexed register
// slots; hist + sort-scatter run from registers; then 8 lanes/node float4
// accumulate, 4-deep unroll (verified R18 inner loop). Overflow: atomic path.
__global__ __launch_bounds__(1024) void bucket_accum(
    const float* __restrict__ input, const int2* __restrict__ recs,
    const int* __restrict__ bbase, float* __restrict__ out, int n_nodes)
{
    __shared__ int2 srec[CAP];             // 48 KB
    __shared__ int lcnt[SPAN];
    __shared__ int lbeg[SPAN];
    __shared__ int lcur[SPAN];
    int b = blockIdx.x;
    int t = threadIdx.x;
    int bstart = bbase[b], bend = bbase[b + 1];
    int base_node = b << SPAN_SHIFT;

    if (bend - bstart <= CAP) {
        // stage this thread's records (<=6) into registers, one global pass
        int i0 = bstart + t;
        bool h0 = i0          < bend;
        bool h1 = i0 + 1024   < bend;
        bool h2 = i0 + 2048   < bend;
        bool h3 = i0 + 3072   < bend;
        bool h4 = i0 + 4096   < bend;
        bool h5 = i0 + 5120   < bend;
        int2 r0, r1, r2, r3, r4, r5;
        if (h0) r0 = recs[i0];
        if (h1) r1 = recs[i0 + 1024];
        if (h2) r2 = recs[i0 + 2048];
        if (h3) r3 = recs[i0 + 3072];
        if (h4) r4 = recs[i0 + 4096];
        if (h5) r5 = recs[i0 + 5120];

        if (t < SPAN) lcnt[t] = 0;
        __syncthreads();
        if (h0) atomicAdd(&lcnt[r0.x & (SPAN - 1)], 1);
        if (h1) atomicAdd(&lcnt[r1.x & (SPAN - 1)], 1);
        if (h2) atomicAdd(&lcnt[r2.x & (SPAN - 1)], 1);
        if (h3) atomicAdd(&lcnt[r3.x & (SPAN - 1)], 1);
        if (h4) atomicAdd(&lcnt[r4.x & (SPAN - 1)], 1);
        if (h5) atomicAdd(&lcnt[r5.x & (SPAN - 1)], 1);
        __syncthreads();
        // exclusive scan over SPAN=128 (masked H-S, uniform barriers)
        int c = (t < SPAN) ? lcnt[t] : 0;
        if (t < SPAN) lbeg[t] = c;
        __syncthreads();
        for (int off = 1; off < SPAN; off <<= 1) {
            int v = (t < SPAN && t >= off) ? lbeg[t - off] : 0;
            __syncthreads();
            if (t < SPAN) lbeg[t] += v;
            __syncthreads();
        }
        if (t < SPAN) {
            int excl = lbeg[t] - c;
            lbeg[t] = excl;
            lcur[t] = excl;
        }
        __syncthreads();
        // sort-scatter from registers into LDS
        if (h0) srec[atomicAdd(&lcur[r0.x & (SPAN - 1)], 1)] = r0;
        if (h1) srec[atomicAdd(&lcur[r1.x & (SPAN - 1)], 1)] = r1;
        if (h2) srec[atomicAdd(&lcur[r2.x & (SPAN - 1)], 1)] = r2;
        if (h3) srec[atomicAdd(&lcur[r3.x & (SPAN - 1)], 1)] = r3;
        if (h4) srec[atomicAdd(&lcur[r4.x & (SPAN - 1)], 1)] = r4;
        if (h5) srec[atomicAdd(&lcur[r5.x & (SPAN - 1)], 1)] = r5;
        __syncthreads();
        // accumulate: 8 lanes per node, float4 per lane, 4-deep unroll
        int node = t >> 3;
        int lane = t & 7;
        int beg = lbeg[node];
        int end = beg + lcnt[node];
        float4 acc = make_float4(0.f, 0.f, 0.f, 0.f);
        int i = beg;
        for (; i + 3 < end; i += 4) {
            int2 q0 = srec[i];
            int2 q1 = srec[i + 1];
            int2 q2 = srec[i + 2];
            int2 q3 = srec[i + 3];
            float4 v0 = ((const float4*)(input + (size_t)(((unsigned)q0.x) >> SPAN_SHIFT) * 32))[lane];
            float4 v1 = ((const float4*)(input + (size_t)(((unsigned)q1.x) >> SPAN_SHIFT) * 32))[lane];
            float4 v2 = ((const float4*)(input + (size_t)(((unsigned)q2.x) >> SPAN_SHIFT) * 32))[lane];
            float4 v3 = ((const float4*)(input + (size_t)(((unsigned)q3.x) >> SPAN_SHIFT) * 32))[lane];
            float w0 = __int_as_float(q0.y);
            float w1 = __int_as_float(q1.y);
            float w2 = __int_as_float(q2.y);
            float w3 = __int_as_float(q3.y);
            acc.x = fmaf(w0, v0.x, acc.x);
            acc.y = fmaf(w0, v0.y, acc.y);
            acc.z = fmaf(w0, v0.z, acc.z);
            acc.w = fmaf(w0, v0.w, acc.w);
            acc.x = fmaf(w1, v1.x, acc.x);
            acc.y = fmaf(w1, v1.y, acc.y);
            acc.z = fmaf(w1, v1.z, acc.z);
            acc.w = fmaf(w1, v1.w, acc.w);
            acc.x = fmaf(w2, v2.x, acc.x);
            acc.y = fmaf(w2, v2.y, acc.y);
            acc.z = fmaf(w2, v2.z, acc.z);
            acc.w = fmaf(w2, v2.w, acc.w);
            acc.x = fmaf(w3, v3.x, acc.x);
            acc.y = fmaf(w3, v3.y, acc.y);
            acc.z = fmaf(w3, v3.z, acc.z);
            acc.w = fmaf(w3, v3.w, acc.w);
        }
        for (; i < end; ++i) {
            int2 q = srec[i];
            float w = __int_as_float(q.y);
            float4 v = ((const float4*)(input + (size_t)(((unsigned)q.x) >> SPAN_SHIFT) * 32))[lane];
            acc.x = fmaf(w, v.x, acc.x);
            acc.y = fmaf(w, v.y, acc.y);
            acc.z = fmaf(w, v.z, acc.z);
            acc.w = fmaf(w, v.w, acc.w);
        }
        int gnode = base_node + node;
        if (gnode < n_nodes)
            ((float4*)(out + (size_t)gnode * 32))[lane] = acc;
    } else {
        // overflow fallback (correctness only; ~never taken on random data)
        for (int i = t; i < SPAN * 32; i += 1024) {
            int gn = base_node + (i >> 5);
            if (gn < n_nodes) out[(size_t)gn * 32 + (i & 31)] = 0.f;
        }
        __syncthreads();
        for (int i = bstart + t; i < bend; i += 1024) {
            int2 r = recs[i];
            float w = __int_as_float(r.y);
            int s = (int)(((unsigned)r.x) >> SPAN_SHIFT);
            int gn = base_node + (r.x & (SPAN - 1));
            if (gn < n_nodes)
                for (int j = 0; j < 32; ++j)
                    atomicAdd(&out[(size_t)gn * 32 + j], w * input[(size_t)s * 32 + j]);
        }
    }
}

// Last-resort fallback (R3): direct atomic scatter.
__global__ __launch_bounds__(NB) void graphconv_scatter(
    const float* __restrict__ input, const int* __restrict__ sidx,
    const int* __restrict__ tidx, const float* __restrict__ enorm,
    const float* __restrict__ esgn, float* __restrict__ out, int n_edges)
{
    int t = blockIdx.x * NB + threadIdx.x;
    int e = t >> 3;
    int sub = t & 7;
    if (e >= n_edges) return;
    int s = sidx[e];
    int d = tidx[e];
    float w = enorm[e] * esgn[e];
    const float4* src = (const float4*)(input + (size_t)s * 32);
    float4 v = src[sub];
    float* op = out + (size_t)d * 32 + sub * 4;
    atomicAdd(op + 0, v.x * w);
    atomicAdd(op + 1, v.y * w);
    atomicAdd(op + 2, v.z * w);
    atomicAdd(op + 3, v.w * w);
}

extern "C" void kernel_launch(void* const* d_in, const int* in_sizes, int n_in,
                              void* d_out, int out_size, void* d_ws, size_t ws_size,
                              hipStream_t stream) {
    const float* input = (const float*)d_in[0];
    const int*   eidx  = (const int*)d_in[1];   // int64 in reference -> int32 here
    const float* enorm = (const float*)d_in[2];
    const float* esgn  = (const float*)d_in[3];
    float*       out   = (float*)d_out;

    int n_edges = in_sizes[1] / 2;             // eidx is (2, n_edges)
    int n_nodes = in_sizes[0] / 32;            // input is (n_nodes, 32)
    const int* sidx = eidx;
    const int* tidx = eidx + n_edges;

    int K = (n_nodes + SPAN - 1) >> SPAN_SHIFT;   // 782 for 100K nodes

    // Workspace: recs[E int2] | cnt[G*KMAX] | pref[G*KMAX] | bbase[KMAX+1]
    size_t need = (size_t)n_edges * 8 +
                  ((size_t)2 * G * KMAX + KMAX + 1) * 4;

    if (ws_size >= need && K <= KMAX) {
        int2* recs  = (int2*)d_ws;
        int*  cnt   = (int*)(recs + n_edges);
        int*  pref  = cnt + (size_t)G * KMAX;
        int*  bbase = pref + (size_t)G * KMAX;

        // chunk size: multiple of 4 so vector loads stay 16B-aligned
        int epb = ((n_edges + G - 1) / G + 3) & ~3;
        int vec = ((n_edges & 3) == 0 &&
                   (((uintptr_t)tidx | (uintptr_t)sidx |
                     (uintptr_t)enorm | (uintptr_t)esgn) & 15) == 0) ? 1 : 0;

        hist_kernel   <<<G,    1024, 0, stream>>>(tidx, cnt, n_edges, epb, vec);
        scanAB_kernel <<<1,    KMAX, 0, stream>>>(cnt, pref, bbase);
        scatter_kernel<<<G,    1024, 0, stream>>>(sidx, tidx, enorm, esgn,
                                                  bbase, pref, recs,
                                                  n_edges, epb, vec);
        bucket_accum  <<<K,    1024, 0, stream>>>(input, recs, bbase,
                                                  out, n_nodes);
    } else {
        hipMemsetAsync(d_out, 0, (size_t)out_size * sizeof(float), stream);
        size_t threads_total = (size_t)n_edges * 8;
        int grid = (int)((threads_total + NB - 1) / NB);
        graphconv_scatter<<<grid, NB, 0, stream>>>(input, sidx, tidx, enorm, esgn,
                                                   out, n_edges);
    }
}